// Round 2
// baseline (857.008 us; speedup 1.0000x reference)
//
#include <hip/hip_runtime.h>
#include <hip/hip_bf16.h>

#define NN 100000
#define INC 1024
#define HID 128
#define NE 1600000
#define NB ((NN + 255) / 256)   // 391 scan blocks

typedef float floatx4 __attribute__((ext_vector_type(4)));
typedef __bf16 bf16x8 __attribute__((ext_vector_type(8)));
typedef unsigned short ushort8v __attribute__((ext_vector_type(8)));
typedef unsigned short ushort4v __attribute__((ext_vector_type(4)));

__device__ __forceinline__ unsigned short f2bf(float f) {
    union { float f; unsigned u; } v; v.f = f;
    unsigned r = v.u + 0x7fffu + ((v.u >> 16) & 1u);   // round-to-nearest-even
    return (unsigned short)(r >> 16);
}

__device__ __forceinline__ float bf_lo(unsigned u) {
    union { unsigned u; float f; } v; v.u = u << 16; return v.f;
}
__device__ __forceinline__ float bf_hi(unsigned u) {
    union { unsigned u; float f; } v; v.u = u & 0xffff0000u; return v.f;
}

// ---- fused: zero degree histogram (blocks [0,NB)) + W transpose->bf16 (blocks [NB,NB+512)) ----
__global__ __launch_bounds__(256) void init_k(int* cnt, const float* __restrict__ W,
                                              unsigned short* __restrict__ Wt) {
    const int b = blockIdx.x;
    if (b < NB) {
        const int i = b * 256 + threadIdx.x;
        if (i < NN) cnt[i] = 0;
    } else {
        const int idx = (b - NB) * 256 + threadIdx.x;   // 131072 total
        const int n = idx >> 10, k = idx & 1023;
        Wt[idx] = f2bf(W[k * HID + n]);
    }
}

// ---- histogram destination degrees (excluding self-loop) ----
__global__ __launch_bounds__(256) void deg_edges_k(const int* __restrict__ col, int* cnt) {
    int e = blockIdx.x * 256 + threadIdx.x;
    if (e < NE) atomicAdd(&cnt[col[e]], 1);
}

// ---- exclusive scan, pass 1: per-block (256-wide); also emit dinv = rsqrt(deg+1) ----
__global__ __launch_bounds__(256) void scan1_k(const int* __restrict__ cnt,
                                               int* __restrict__ excl, int* __restrict__ bsum,
                                               float* __restrict__ dinv) {
    __shared__ int sh[256];
    const int t = threadIdx.x, b = blockIdx.x;
    const int idx = b * 256 + t;
    const int v = (idx < NN) ? cnt[idx] : 0;
    sh[t] = v;
    __syncthreads();
#pragma unroll
    for (int off = 1; off < 256; off <<= 1) {
        const int x = sh[t];
        const int y = (t >= off) ? sh[t - off] : 0;
        __syncthreads();
        sh[t] = x + y;
        __syncthreads();
    }
    if (idx < NN) {
        excl[idx] = sh[t] - v;
        dinv[idx] = rsqrtf((float)(v + 1));
    }
    if (t == 255) bsum[b] = sh[255];
}

// ---- exclusive scan, pass 2: scan the 391 block sums (single block, 512 thr) ----
__global__ __launch_bounds__(512) void scan2_k(const int* __restrict__ bsum, int* __restrict__ boff) {
    __shared__ int sh[512];
    const int t = threadIdx.x;
    const int v = (t < NB) ? bsum[t] : 0;
    sh[t] = v;
    __syncthreads();
#pragma unroll
    for (int off = 1; off < 512; off <<= 1) {
        const int x = sh[t];
        const int y = (t >= off) ? sh[t - off] : 0;
        __syncthreads();
        sh[t] = x + y;
        __syncthreads();
    }
    if (t < NB) boff[t] = sh[t] - v;
}

// ---- scan pass 3: rowptr = excl + boff; also init cursor; rowptr[NN] = NE ----
__global__ __launch_bounds__(256) void scan3_k(const int* __restrict__ excl, const int* __restrict__ boff,
                                               int* __restrict__ rowptr, int* __restrict__ cursor) {
    const int idx = blockIdx.x * 256 + threadIdx.x;
    if (idx < NN) {
        const int v = excl[idx] + boff[blockIdx.x];
        rowptr[idx] = v;
        cursor[idx] = v;
    }
    if (idx == 0) rowptr[NN] = NE;
}

// ---- bucket edges by destination: ssrc[rowptr[c] ...] = srcs of c ----
__global__ __launch_bounds__(256) void fill_k(const int* __restrict__ ei,
                                              int* cursor, int* __restrict__ ssrc) {
    const int e = blockIdx.x * 256 + threadIdx.x;
    if (e < NE) {
        const int r = ei[e];
        const int c = ei[NE + e];
        const int pos = atomicAdd(&cursor[c], 1);
        ssrc[pos] = r;
    }
}

// ---- GEMM: hp = bf16( (x @ W) * dinv[row] ), BM=128, reg-prefetch dbuf LDS ----
// 4 waves; wave w owns rows [w*32, w*32+32): 2 row-frags x 8 col-frags.
// Per wave per K-step: 10 ds_read_b128 -> 16 MFMA.
__global__ __launch_bounds__(256) void gemm_hp_k(
    const float* __restrict__ x, const unsigned short* __restrict__ Wt,
    const float* __restrict__ dinv, unsigned short* __restrict__ hp)
{
    __shared__ unsigned short As[2][128 * 40];
    __shared__ unsigned short Bs[2][128 * 40];
    const int tid  = threadIdx.x;
    const int lane = tid & 63;
    const int wave = tid >> 6;
    const int q    = lane >> 4;
    const int l16  = lane & 15;
    const int brow = blockIdx.x * 128;

    // staging geometry: 2 threads per row, each covers 16 elems (half of BK=32)
    const int srow = tid >> 1;          // 0..127
    const int skk  = (tid & 1) * 16;    // 0 or 16

    floatx4 acc[2][8];
#pragma unroll
    for (int f = 0; f < 2; ++f)
#pragma unroll
        for (int t = 0; t < 8; ++t) acc[f][t] = (floatx4){0.f, 0.f, 0.f, 0.f};

    float4   va[4];
    ushort8v vb[2];

    const int ag = brow + srow;
    const bool aok = (ag < NN);
    const float* __restrict__ xrow = x + (size_t)ag * INC + skk;
    const unsigned short* __restrict__ wrow = Wt + (size_t)srow * INC + skk;

    // prologue: stage k0 = 0 into registers
    {
#pragma unroll
        for (int j = 0; j < 4; ++j) {
            float4 v = make_float4(0.f, 0.f, 0.f, 0.f);
            if (aok) v = *(const float4*)&xrow[4 * j];
            va[j] = v;
        }
        vb[0] = *(const ushort8v*)&wrow[0];
        vb[1] = *(const ushort8v*)&wrow[8];
    }

    int buf = 0;
    for (int k0 = 0; k0 < INC; k0 += 32) {
        // regs -> LDS[buf]
        {
            ushort8v w0, w1;
            w0[0] = f2bf(va[0].x); w0[1] = f2bf(va[0].y); w0[2] = f2bf(va[0].z); w0[3] = f2bf(va[0].w);
            w0[4] = f2bf(va[1].x); w0[5] = f2bf(va[1].y); w0[6] = f2bf(va[1].z); w0[7] = f2bf(va[1].w);
            w1[0] = f2bf(va[2].x); w1[1] = f2bf(va[2].y); w1[2] = f2bf(va[2].z); w1[3] = f2bf(va[2].w);
            w1[4] = f2bf(va[3].x); w1[5] = f2bf(va[3].y); w1[6] = f2bf(va[3].z); w1[7] = f2bf(va[3].w);
            *(ushort8v*)&As[buf][srow * 40 + skk]     = w0;
            *(ushort8v*)&As[buf][srow * 40 + skk + 8] = w1;
            *(ushort8v*)&Bs[buf][srow * 40 + skk]     = vb[0];
            *(ushort8v*)&Bs[buf][srow * 40 + skk + 8] = vb[1];
        }
        __syncthreads();

        // issue next tile's global loads (overlap with MFMA below)
        const int kn = k0 + 32;
        if (kn < INC) {
#pragma unroll
            for (int j = 0; j < 4; ++j) {
                float4 v = make_float4(0.f, 0.f, 0.f, 0.f);
                if (aok) v = *(const float4*)&xrow[kn + 4 * j];
                va[j] = v;
            }
            vb[0] = *(const ushort8v*)&wrow[kn];
            vb[1] = *(const ushort8v*)&wrow[kn + 8];
        }

        const bf16x8 af0 = *(const bf16x8*)&As[buf][(wave * 32 + l16) * 40 + q * 8];
        const bf16x8 af1 = *(const bf16x8*)&As[buf][(wave * 32 + 16 + l16) * 40 + q * 8];
#pragma unroll
        for (int t = 0; t < 8; ++t) {
            const bf16x8 bfv = *(const bf16x8*)&Bs[buf][(t * 16 + l16) * 40 + q * 8];
            acc[0][t] = __builtin_amdgcn_mfma_f32_16x16x32_bf16(af0, bfv, acc[0][t], 0, 0, 0);
            acc[1][t] = __builtin_amdgcn_mfma_f32_16x16x32_bf16(af1, bfv, acc[1][t], 0, 0, 0);
        }
        buf ^= 1;
        // single barrier per K-step: next store into this buffer only happens after
        // the NEXT iteration's barrier, by which time all waves' ds_reads drained.
    }

#pragma unroll
    for (int f = 0; f < 2; ++f) {
#pragma unroll
        for (int r = 0; r < 4; ++r) {
            const int row = brow + wave * 32 + f * 16 + q * 4 + r;
            if (row < NN) {
                const float d = dinv[row];
#pragma unroll
                for (int t = 0; t < 8; ++t) {
                    const int col = t * 16 + l16;
                    hp[(size_t)row * HID + col] = f2bf(acc[f][t][r] * d);
                }
            }
        }
    }
}

// ---- aggregation: one wave per dst; out[d] = dinv[d] * (hp[d] + sum hp[src]) ----
// hp is bf16, 256 B/row; lane owns 2 cols packed in one dword.
// Edge walk is wave-uniform: srcs forced to SGPRs -> saddr gathers, no shuffles.
__global__ __launch_bounds__(256) void agg_k(const int* __restrict__ rowptr,
                                             const int* __restrict__ ssrc,
                                             const unsigned short* __restrict__ hp,
                                             const float* __restrict__ dinv,
                                             float* __restrict__ out)
{
    const int w = (blockIdx.x * 256 + threadIdx.x) >> 6;   // dst node (wave-uniform)
    const int lane = threadIdx.x & 63;
    if (w >= NN) return;
    const int s = __builtin_amdgcn_readfirstlane(rowptr[w]);
    const int e = __builtin_amdgcn_readfirstlane(rowptr[w + 1]);
    const unsigned* __restrict__ hp32 = (const unsigned*)hp;   // row stride = 64 dwords

    const unsigned uself = hp32[(size_t)w * 64 + lane];
    float ax = bf_lo(uself), ay = bf_hi(uself);

    int i = s;
    for (; i + 8 <= e; i += 8) {
        const int s0 = __builtin_amdgcn_readfirstlane(ssrc[i + 0]);
        const int s1 = __builtin_amdgcn_readfirstlane(ssrc[i + 1]);
        const int s2 = __builtin_amdgcn_readfirstlane(ssrc[i + 2]);
        const int s3 = __builtin_amdgcn_readfirstlane(ssrc[i + 3]);
        const int s4 = __builtin_amdgcn_readfirstlane(ssrc[i + 4]);
        const int s5 = __builtin_amdgcn_readfirstlane(ssrc[i + 5]);
        const int s6 = __builtin_amdgcn_readfirstlane(ssrc[i + 6]);
        const int s7 = __builtin_amdgcn_readfirstlane(ssrc[i + 7]);
        const unsigned v0 = hp32[(size_t)s0 * 64 + lane];
        const unsigned v1 = hp32[(size_t)s1 * 64 + lane];
        const unsigned v2 = hp32[(size_t)s2 * 64 + lane];
        const unsigned v3 = hp32[(size_t)s3 * 64 + lane];
        const unsigned v4 = hp32[(size_t)s4 * 64 + lane];
        const unsigned v5 = hp32[(size_t)s5 * 64 + lane];
        const unsigned v6 = hp32[(size_t)s6 * 64 + lane];
        const unsigned v7 = hp32[(size_t)s7 * 64 + lane];
        ax += bf_lo(v0) + bf_lo(v1) + bf_lo(v2) + bf_lo(v3)
            + bf_lo(v4) + bf_lo(v5) + bf_lo(v6) + bf_lo(v7);
        ay += bf_hi(v0) + bf_hi(v1) + bf_hi(v2) + bf_hi(v3)
            + bf_hi(v4) + bf_hi(v5) + bf_hi(v6) + bf_hi(v7);
    }
    for (; i < e; ++i) {
        const int sj = __builtin_amdgcn_readfirstlane(ssrc[i]);
        const unsigned v = hp32[(size_t)sj * 64 + lane];
        ax += bf_lo(v);
        ay += bf_hi(v);
    }

    const float d = dinv[w];
    float2 r;
    r.x = ax * d;
    r.y = ay * d;
    *(float2*)&out[(size_t)w * HID + (size_t)lane * 2] = r;
}

extern "C" void kernel_launch(void* const* d_in, const int* in_sizes, int n_in,
                              void* d_out, int out_size, void* d_ws, size_t ws_size,
                              hipStream_t stream) {
    const float* x  = (const float*)d_in[0];
    const float* W  = (const float*)d_in[1];
    const int*   ei = (const int*)d_in[2];
    float* out = (float*)d_out;

    // workspace layout (bytes)
    char* p = (char*)d_ws;
    unsigned short* hp = (unsigned short*)p; p += (size_t)NN * HID * 2;  // 25.6 MB
    int*   cnt     = (int*)p;              p += (size_t)NN * 4;
    int*   rowptr  = (int*)p;              p += (size_t)(NN + 4) * 4;
    int*   cursor  = (int*)p;              p += (size_t)NN * 4;
    int*   excl    = (int*)p;              p += (size_t)NN * 4;
    float* dinv    = (float*)p;            p += (size_t)NN * 4;
    unsigned short* Wt = (unsigned short*)p; p += (size_t)INC * HID * 2;
    int*   bsum    = (int*)p;              p += 512 * 4;
    int*   boff    = (int*)p;              p += 512 * 4;
    int*   ssrc    = (int*)p;              p += (size_t)NE * 4;          // 6.4 MB

    init_k     <<<NB + (INC * HID) / 256, 256, 0, stream>>>(cnt, W, Wt);
    deg_edges_k<<<(NE + 255) / 256, 256, 0, stream>>>(ei + NE, cnt);
    scan1_k    <<<NB, 256, 0, stream>>>(cnt, excl, bsum, dinv);
    scan2_k    <<<1, 512, 0, stream>>>(bsum, boff);
    scan3_k    <<<NB, 256, 0, stream>>>(excl, boff, rowptr, cursor);
    fill_k     <<<(NE + 255) / 256, 256, 0, stream>>>(ei, cursor, ssrc);
    gemm_hp_k  <<<(NN + 127) / 128, 256, 0, stream>>>(x, Wt, dinv, hp);
    agg_k      <<<(NN * 64 + 255) / 256, 256, 0, stream>>>(rowptr, ssrc, hp, dinv, out);
}